// Round 1
// baseline (2278.108 us; speedup 1.0000x reference)
//
#include <hip/hip_runtime.h>

#define H    128
#define RBF  50
#define RBFP 52   // padded so float4 rows stay 16B-aligned (52*4=208, 208%16==0)
#define EB   64   // edges per block
#define NB   32   // nodes per block

__device__ __forceinline__ float silu_f(float a) {
    return a / (1.0f + __expf(-a));
}

// h = x @ dW + db        [N,128] = [N,128]@[128,128]
__global__ __launch_bounds__(256) void compute_h_kernel(
    const float* __restrict__ x, const float* __restrict__ dW,
    const float* __restrict__ db, float* __restrict__ h, int N)
{
    __shared__ float xs[NB][H];
    const int tid = threadIdx.x;
    const int n0  = blockIdx.x * NB;

    for (int idx = tid; idx < NB * H; idx += 256) {
        int r = idx >> 7, c = idx & (H - 1);
        int n = n0 + r;
        xs[r][c] = (n < N) ? x[(size_t)n * H + c] : 0.f;
    }
    __syncthreads();

    const int j  = tid & (H - 1);
    const int rb = (tid >> 7) * 16;   // two row-halves of 16

    float acc[16];
    const float b = db[j];
#pragma unroll
    for (int r = 0; r < 16; ++r) acc[r] = b;

    for (int kq = 0; kq < H / 4; ++kq) {
        const int k = kq * 4;
        const float w0 = dW[(k + 0) * H + j];
        const float w1 = dW[(k + 1) * H + j];
        const float w2 = dW[(k + 2) * H + j];
        const float w3 = dW[(k + 3) * H + j];
#pragma unroll
        for (int r = 0; r < 16; ++r) {
            const float4 v = *(const float4*)&xs[rb + r][k];
            acc[r] = fmaf(v.x, w0, fmaf(v.y, w1, fmaf(v.z, w2, fmaf(v.w, w3, acc[r]))));
        }
    }

#pragma unroll
    for (int r = 0; r < 16; ++r) {
        int n = n0 + rb + r;
        if (n < N) h[(size_t)n * H + j] = acc[r];
    }
}

// Fused per-edge: filters = silu(ea@fW1+fb1)@fW2+fb2 ; msg = h[src]*filters ;
// atomicAdd into out[dst]
__global__ __launch_bounds__(256) void edge_kernel(
    const float* __restrict__ ea,
    const int*   __restrict__ src_idx, const int* __restrict__ dst_idx,
    const float* __restrict__ fW1, const float* __restrict__ fb1,
    const float* __restrict__ fW2, const float* __restrict__ fb2,
    const float* __restrict__ h, float* __restrict__ out, int E)
{
    __shared__ float ea_s[EB][RBFP];
    __shared__ float t_s[EB][H];
    __shared__ int   src_s[EB];
    __shared__ int   dst_s[EB];

    const int tid = threadIdx.x;
    const int e0  = blockIdx.x * EB;

    // stage edge_attr tile (zero-pad cols 50,51 and OOB edges)
    for (int idx = tid; idx < EB * RBFP; idx += 256) {
        int r = idx / RBFP, k = idx % RBFP;
        int e = e0 + r;
        ea_s[r][k] = (k < RBF && e < E) ? ea[(size_t)e * RBF + k] : 0.f;
    }
    if (tid < EB) {
        int e = e0 + tid;
        src_s[tid] = (e < E) ? src_idx[e] : 0;
        dst_s[tid] = (e < E) ? dst_idx[e] : -1;
    }
    __syncthreads();

    const int j  = tid & (H - 1);
    const int rb = (tid >> 7) * 32;   // 32 edge-rows per thread

    float acc[32];
    {
        const float b1 = fb1[j];
#pragma unroll
        for (int r = 0; r < 32; ++r) acc[r] = b1;
    }

    // stage 1: t = ea @ fW1 + fb1   (K=50, padded to 52)
    for (int kq = 0; kq < RBFP / 4; ++kq) {
        const int k = kq * 4;
        const float w0 = fW1[(k + 0) * H + j];
        const float w1 = fW1[(k + 1) * H + j];
        const float w2 = (k + 2 < RBF) ? fW1[(k + 2) * H + j] : 0.f;
        const float w3 = (k + 3 < RBF) ? fW1[(k + 3) * H + j] : 0.f;
#pragma unroll
        for (int r = 0; r < 32; ++r) {
            const float4 v = *(const float4*)&ea_s[rb + r][k];
            acc[r] = fmaf(v.x, w0, fmaf(v.y, w1, fmaf(v.z, w2, fmaf(v.w, w3, acc[r]))));
        }
    }

    // silu -> LDS t tile
#pragma unroll
    for (int r = 0; r < 32; ++r) t_s[rb + r][j] = silu_f(acc[r]);
    __syncthreads();

    // stage 2: filters = t @ fW2 + fb2   (K=128)
    {
        const float b2 = fb2[j];
#pragma unroll
        for (int r = 0; r < 32; ++r) acc[r] = b2;
    }
    for (int kq = 0; kq < H / 4; ++kq) {
        const int k = kq * 4;
        const float w0 = fW2[(k + 0) * H + j];
        const float w1 = fW2[(k + 1) * H + j];
        const float w2 = fW2[(k + 2) * H + j];
        const float w3 = fW2[(k + 3) * H + j];
#pragma unroll
        for (int r = 0; r < 32; ++r) {
            const float4 v = *(const float4*)&t_s[rb + r][k];
            acc[r] = fmaf(v.x, w0, fmaf(v.y, w1, fmaf(v.z, w2, fmaf(v.w, w3, acc[r]))));
        }
    }

    // stage 3: gather h[src], multiply, scatter-add to out[dst]
#pragma unroll 4
    for (int r = 0; r < 32; ++r) {
        const int er = rb + r;
        const int s = src_s[er];
        const int d = dst_s[er];
        if (d >= 0) {
            const float m = h[(size_t)s * H + j] * acc[r];
            unsafeAtomicAdd(&out[(size_t)d * H + j], m);
        }
    }
}

// out = x + silu(agg@uW1+ub1)@uW2+ub2 ; agg lives in `out` on entry (row-wise in-place)
__global__ __launch_bounds__(256) void update_kernel(
    const float* __restrict__ x,
    const float* __restrict__ uW1, const float* __restrict__ ub1,
    const float* __restrict__ uW2, const float* __restrict__ ub2,
    float* __restrict__ out, int N)
{
    __shared__ float as[NB][H];
    __shared__ float ts[NB][H];
    const int tid = threadIdx.x;
    const int n0  = blockIdx.x * NB;

    for (int idx = tid; idx < NB * H; idx += 256) {
        int r = idx >> 7, c = idx & (H - 1);
        int n = n0 + r;
        as[r][c] = (n < N) ? out[(size_t)n * H + c] : 0.f;
    }
    __syncthreads();

    const int j  = tid & (H - 1);
    const int rb = (tid >> 7) * 16;

    float acc[16];
    {
        const float b1 = ub1[j];
#pragma unroll
        for (int r = 0; r < 16; ++r) acc[r] = b1;
    }
    for (int kq = 0; kq < H / 4; ++kq) {
        const int k = kq * 4;
        const float w0 = uW1[(k + 0) * H + j];
        const float w1 = uW1[(k + 1) * H + j];
        const float w2 = uW1[(k + 2) * H + j];
        const float w3 = uW1[(k + 3) * H + j];
#pragma unroll
        for (int r = 0; r < 16; ++r) {
            const float4 v = *(const float4*)&as[rb + r][k];
            acc[r] = fmaf(v.x, w0, fmaf(v.y, w1, fmaf(v.z, w2, fmaf(v.w, w3, acc[r]))));
        }
    }
#pragma unroll
    for (int r = 0; r < 16; ++r) ts[rb + r][j] = silu_f(acc[r]);
    __syncthreads();

    {
        const float b2 = ub2[j];
#pragma unroll
        for (int r = 0; r < 16; ++r) acc[r] = b2;
    }
    for (int kq = 0; kq < H / 4; ++kq) {
        const int k = kq * 4;
        const float w0 = uW2[(k + 0) * H + j];
        const float w1 = uW2[(k + 1) * H + j];
        const float w2 = uW2[(k + 2) * H + j];
        const float w3 = uW2[(k + 3) * H + j];
#pragma unroll
        for (int r = 0; r < 16; ++r) {
            const float4 v = *(const float4*)&ts[rb + r][k];
            acc[r] = fmaf(v.x, w0, fmaf(v.y, w1, fmaf(v.z, w2, fmaf(v.w, w3, acc[r]))));
        }
    }

#pragma unroll
    for (int r = 0; r < 16; ++r) {
        int n = n0 + rb + r;
        if (n < N) out[(size_t)n * H + j] = x[(size_t)n * H + j] + acc[r];
    }
}

extern "C" void kernel_launch(void* const* d_in, const int* in_sizes, int n_in,
                              void* d_out, int out_size, void* d_ws, size_t ws_size,
                              hipStream_t stream) {
    const float* x   = (const float*)d_in[0];
    const int*   ei  = (const int*)  d_in[1];
    const float* ea  = (const float*)d_in[2];
    const float* fW1 = (const float*)d_in[3];
    const float* fb1 = (const float*)d_in[4];
    const float* fW2 = (const float*)d_in[5];
    const float* fb2 = (const float*)d_in[6];
    const float* dW  = (const float*)d_in[7];
    const float* db  = (const float*)d_in[8];
    const float* uW1 = (const float*)d_in[9];
    const float* ub1 = (const float*)d_in[10];
    const float* uW2 = (const float*)d_in[11];
    const float* ub2 = (const float*)d_in[12];

    float* out = (float*)d_out;
    float* h   = (float*)d_ws;   // [N,H] fp32 = 25.6 MB

    const int N = in_sizes[0] / H;
    const int E = in_sizes[1] / 2;
    const int* src = ei;
    const int* dst = ei + E;

    // agg accumulates directly into d_out (zeroed first)
    hipMemsetAsync(out, 0, (size_t)N * H * sizeof(float), stream);

    compute_h_kernel<<<(N + NB - 1) / NB, 256, 0, stream>>>(x, dW, db, h, N);
    edge_kernel<<<(E + EB - 1) / EB, 256, 0, stream>>>(
        ea, src, dst, fW1, fb1, fW2, fb2, h, out, E);
    update_kernel<<<(N + NB - 1) / NB, 256, 0, stream>>>(
        x, uW1, ub1, uW2, ub2, out, N);
}

// Round 2
// 1204.362 us; speedup vs baseline: 1.8915x; 1.8915x over previous
//
#include <hip/hip_runtime.h>

#define H    128
#define RBF  50
#define K1   64    // stage-1 K padded 50 -> 64
#define EB   64    // edges per tile
#define NB   32

typedef _Float16 f16;
typedef _Float16 f16x8 __attribute__((ext_vector_type(8)));
typedef float    f32x4 __attribute__((ext_vector_type(4)));

// LDS row strides (f16 elems): +8 pad => 2-way bank aliasing (free), 16B-aligned rows
#define EA_LD 72    // 144 B
#define T_LD  136   // 272 B

__device__ __forceinline__ float silu_f(float a) {
    return a / (1.0f + __expf(-a));
}

// Wt1[n][k] = fW1[k][n] (f16, k in [0,64), zero-padded); Wt2[n][k] = fW2[k][n]
__global__ __launch_bounds__(256) void convert_weights_kernel(
    const float* __restrict__ fW1, const float* __restrict__ fW2,
    f16* __restrict__ Wt1, f16* __restrict__ Wt2)
{
    int i = blockIdx.x * 256 + threadIdx.x;
    if (i < H * K1) {
        int n = i >> 6, k = i & (K1 - 1);
        Wt1[i] = (k < RBF) ? (f16)fW1[k * H + n] : (f16)0.f;
    }
    int j = i - H * K1;
    if (j >= 0 && j < H * H) {
        int n = j >> 7, k = j & (H - 1);
        Wt2[j] = (f16)fW2[k * H + n];
    }
}

// h = x @ dW + db   [N,128] fp32 compute, f16 store
__global__ __launch_bounds__(256) void compute_h_kernel(
    const float* __restrict__ x, const float* __restrict__ dW,
    const float* __restrict__ db, f16* __restrict__ h, int N)
{
    __shared__ float xs[NB][H];
    const int tid = threadIdx.x;
    const int n0  = blockIdx.x * NB;

    for (int idx = tid; idx < NB * H; idx += 256) {
        int r = idx >> 7, c = idx & (H - 1);
        int n = n0 + r;
        xs[r][c] = (n < N) ? x[(size_t)n * H + c] : 0.f;
    }
    __syncthreads();

    const int j  = tid & (H - 1);
    const int rb = (tid >> 7) * 16;

    float acc[16];
    const float b = db[j];
#pragma unroll
    for (int r = 0; r < 16; ++r) acc[r] = b;

    for (int kq = 0; kq < H / 4; ++kq) {
        const int k = kq * 4;
        const float w0 = dW[(k + 0) * H + j];
        const float w1 = dW[(k + 1) * H + j];
        const float w2 = dW[(k + 2) * H + j];
        const float w3 = dW[(k + 3) * H + j];
#pragma unroll
        for (int r = 0; r < 16; ++r) {
            const float4 v = *(const float4*)&xs[rb + r][k];
            acc[r] = fmaf(v.x, w0, fmaf(v.y, w1, fmaf(v.z, w2, fmaf(v.w, w3, acc[r]))));
        }
    }
#pragma unroll
    for (int r = 0; r < 16; ++r) {
        int n = n0 + rb + r;
        if (n < N) h[(size_t)n * H + j] = (f16)acc[r];
    }
}

// Fused MFMA edge kernel: filters = silu(ea@W1+b1)@W2+b2 ; msg = h[src]*filters ;
// atomic scatter-add into out[dst]. B-frags persistent in registers, grid-stride tiles.
__global__ __launch_bounds__(256, 2) void edge_mfma_kernel(
    const float* __restrict__ ea,
    const int* __restrict__ src_idx, const int* __restrict__ dst_idx,
    const f16* __restrict__ Wt1, const f16* __restrict__ Wt2,
    const float* __restrict__ fb1, const float* __restrict__ fb2,
    const f16* __restrict__ h, float* __restrict__ out, int E, int ntiles)
{
    __shared__ __align__(16) f16 ea_s[EB][EA_LD];
    __shared__ __align__(16) f16 t_s[EB][T_LD];
    __shared__ int src_s[EB];
    __shared__ int dst_s[EB];

    const int tid  = threadIdx.x;
    const int lane = tid & 63;
    const int wv   = tid >> 6;        // 4 waves
    const int wr   = (wv >> 1) * 32;  // wave row base: 0 or 32
    const int wc   = (wv & 1) * 64;   // wave col base: 0 or 64
    const int fr   = lane & 15;       // frag row (A) / col (B,C)
    const int qw   = lane >> 4;       // quarter-wave
    const int kb   = qw * 8;          // frag k-block base

    // ---- persistent B fragments (loaded once per block) ----
    f16x8 B1[4][2];   // stage-1 weights: 4 col-tiles x 2 k-steps
    f16x8 B2[4][4];   // stage-2 weights: 4 col-tiles x 4 k-steps
    float b1v[4], b2v[4];
#pragma unroll
    for (int ct = 0; ct < 4; ++ct) {
        const int col = wc + ct * 16 + fr;
#pragma unroll
        for (int ks = 0; ks < 2; ++ks)
            B1[ct][ks] = *(const f16x8*)&Wt1[col * K1 + ks * 32 + kb];
#pragma unroll
        for (int ks = 0; ks < 4; ++ks)
            B2[ct][ks] = *(const f16x8*)&Wt2[col * H + ks * 32 + kb];
        b1v[ct] = fb1[col];
        b2v[ct] = fb2[col];
    }

    for (int t = blockIdx.x; t < ntiles; t += gridDim.x) {
        const int e0 = t * EB;
        __syncthreads();   // prev tile's LDS reads done before restaging

        // ---- stage ea tile fp32 -> f16 (coalesced 8B/lane), zero-pad k 50..63 ----
        for (int idx = tid; idx < EB * 32; idx += 256) {
            int r = idx >> 5, p = (idx & 31) * 2;
            f16 a = (f16)0.f, b = (f16)0.f;
            int e = e0 + r;
            if (p < RBF && e < E) {
                const float2 v = *(const float2*)&ea[(size_t)e * RBF + p];
                a = (f16)v.x; b = (f16)v.y;
            }
            ea_s[r][p]     = a;
            ea_s[r][p + 1] = b;
        }
        if (tid < EB) {
            int e = e0 + tid;
            src_s[tid] = (e < E) ? src_idx[e] : 0;
            dst_s[tid] = (e < E) ? dst_idx[e] : -1;
        }
        __syncthreads();

        // ---- stage 1: t = ea @ W1 + b1 ----
        f32x4 acc[2][4];
#pragma unroll
        for (int rt = 0; rt < 2; ++rt)
#pragma unroll
            for (int ct = 0; ct < 4; ++ct)
                acc[rt][ct] = (f32x4){b1v[ct], b1v[ct], b1v[ct], b1v[ct]};

#pragma unroll
        for (int ks = 0; ks < 2; ++ks) {
            const f16x8 A0 = *(const f16x8*)&ea_s[wr + fr][ks * 32 + kb];
            const f16x8 A1 = *(const f16x8*)&ea_s[wr + 16 + fr][ks * 32 + kb];
#pragma unroll
            for (int ct = 0; ct < 4; ++ct) {
                acc[0][ct] = __builtin_amdgcn_mfma_f32_16x16x32_f16(A0, B1[ct][ks], acc[0][ct], 0, 0, 0);
                acc[1][ct] = __builtin_amdgcn_mfma_f32_16x16x32_f16(A1, B1[ct][ks], acc[1][ct], 0, 0, 0);
            }
        }

        // ---- silu -> t_s (f16) ----
#pragma unroll
        for (int rt = 0; rt < 2; ++rt)
#pragma unroll
            for (int ct = 0; ct < 4; ++ct)
#pragma unroll
                for (int m = 0; m < 4; ++m) {
                    const int row = wr + rt * 16 + qw * 4 + m;
                    const int col = wc + ct * 16 + fr;
                    t_s[row][col] = (f16)silu_f(acc[rt][ct][m]);
                }
        __syncthreads();

        // ---- stage 2: filters = t @ W2 + b2 ----
        f32x4 acc2[2][4];
#pragma unroll
        for (int rt = 0; rt < 2; ++rt)
#pragma unroll
            for (int ct = 0; ct < 4; ++ct)
                acc2[rt][ct] = (f32x4){b2v[ct], b2v[ct], b2v[ct], b2v[ct]};

#pragma unroll
        for (int ks = 0; ks < 4; ++ks) {
            const f16x8 A0 = *(const f16x8*)&t_s[wr + fr][ks * 32 + kb];
            const f16x8 A1 = *(const f16x8*)&t_s[wr + 16 + fr][ks * 32 + kb];
#pragma unroll
            for (int ct = 0; ct < 4; ++ct) {
                acc2[0][ct] = __builtin_amdgcn_mfma_f32_16x16x32_f16(A0, B2[ct][ks], acc2[0][ct], 0, 0, 0);
                acc2[1][ct] = __builtin_amdgcn_mfma_f32_16x16x32_f16(A1, B2[ct][ks], acc2[1][ct], 0, 0, 0);
            }
        }

        // ---- stage 3: gather h[src] (f16), multiply, atomic scatter-add ----
#pragma unroll
        for (int rt = 0; rt < 2; ++rt)
#pragma unroll
            for (int ct = 0; ct < 4; ++ct)
#pragma unroll
                for (int m = 0; m < 4; ++m) {
                    const int er  = wr + rt * 16 + qw * 4 + m;
                    const int col = wc + ct * 16 + fr;
                    const int s = src_s[er];
                    const int d = dst_s[er];
                    if (d >= 0) {
                        const float msg = (float)h[(size_t)s * H + col] * acc2[rt][ct][m];
                        unsafeAtomicAdd(&out[(size_t)d * H + col], msg);
                    }
                }
    }
}

// out = x + silu(agg@uW1+ub1)@uW2+ub2 ; agg lives in `out` on entry
__global__ __launch_bounds__(256) void update_kernel(
    const float* __restrict__ x,
    const float* __restrict__ uW1, const float* __restrict__ ub1,
    const float* __restrict__ uW2, const float* __restrict__ ub2,
    float* __restrict__ out, int N)
{
    __shared__ float as[NB][H];
    __shared__ float ts[NB][H];
    const int tid = threadIdx.x;
    const int n0  = blockIdx.x * NB;

    for (int idx = tid; idx < NB * H; idx += 256) {
        int r = idx >> 7, c = idx & (H - 1);
        int n = n0 + r;
        as[r][c] = (n < N) ? out[(size_t)n * H + c] : 0.f;
    }
    __syncthreads();

    const int j  = tid & (H - 1);
    const int rb = (tid >> 7) * 16;

    float acc[16];
    {
        const float b1 = ub1[j];
#pragma unroll
        for (int r = 0; r < 16; ++r) acc[r] = b1;
    }
    for (int kq = 0; kq < H / 4; ++kq) {
        const int k = kq * 4;
        const float w0 = uW1[(k + 0) * H + j];
        const float w1 = uW1[(k + 1) * H + j];
        const float w2 = uW1[(k + 2) * H + j];
        const float w3 = uW1[(k + 3) * H + j];
#pragma unroll
        for (int r = 0; r < 16; ++r) {
            const float4 v = *(const float4*)&as[rb + r][k];
            acc[r] = fmaf(v.x, w0, fmaf(v.y, w1, fmaf(v.z, w2, fmaf(v.w, w3, acc[r]))));
        }
    }
#pragma unroll
    for (int r = 0; r < 16; ++r) ts[rb + r][j] = silu_f(acc[r]);
    __syncthreads();

    {
        const float b2 = ub2[j];
#pragma unroll
        for (int r = 0; r < 16; ++r) acc[r] = b2;
    }
    for (int kq = 0; kq < H / 4; ++kq) {
        const int k = kq * 4;
        const float w0 = uW2[(k + 0) * H + j];
        const float w1 = uW2[(k + 1) * H + j];
        const float w2 = uW2[(k + 2) * H + j];
        const float w3 = uW2[(k + 3) * H + j];
#pragma unroll
        for (int r = 0; r < 16; ++r) {
            const float4 v = *(const float4*)&ts[rb + r][k];
            acc[r] = fmaf(v.x, w0, fmaf(v.y, w1, fmaf(v.z, w2, fmaf(v.w, w3, acc[r]))));
        }
    }
#pragma unroll
    for (int r = 0; r < 16; ++r) {
        int n = n0 + rb + r;
        if (n < N) out[(size_t)n * H + j] = x[(size_t)n * H + j] + acc[r];
    }
}

extern "C" void kernel_launch(void* const* d_in, const int* in_sizes, int n_in,
                              void* d_out, int out_size, void* d_ws, size_t ws_size,
                              hipStream_t stream) {
    const float* x   = (const float*)d_in[0];
    const int*   ei  = (const int*)  d_in[1];
    const float* ea  = (const float*)d_in[2];
    const float* fW1 = (const float*)d_in[3];
    const float* fb1 = (const float*)d_in[4];
    const float* fW2 = (const float*)d_in[5];
    const float* fb2 = (const float*)d_in[6];
    const float* dW  = (const float*)d_in[7];
    const float* db  = (const float*)d_in[8];
    const float* uW1 = (const float*)d_in[9];
    const float* ub1 = (const float*)d_in[10];
    const float* uW2 = (const float*)d_in[11];
    const float* ub2 = (const float*)d_in[12];

    float* out = (float*)d_out;

    const int N = in_sizes[0] / H;
    const int E = in_sizes[1] / 2;
    const int* src = ei;
    const int* dst = ei + E;

    // workspace layout (total < 12.9 MB, well under the >=25.6 MB proven in R1):
    //   h_f16  [N*H]    at +0
    //   Wt1    [128*64] f16
    //   Wt2    [128*128] f16
    char* ws = (char*)d_ws;
    f16* h   = (f16*)ws;
    size_t off = (size_t)N * H * sizeof(f16);
    f16* Wt1 = (f16*)(ws + off);             off += (size_t)H * K1 * sizeof(f16);
    f16* Wt2 = (f16*)(ws + off);

    hipMemsetAsync(out, 0, (size_t)N * H * sizeof(float), stream);

    convert_weights_kernel<<<(H * K1 + H * H + 255) / 256, 256, 0, stream>>>(fW1, fW2, Wt1, Wt2);
    compute_h_kernel<<<(N + NB - 1) / NB, 256, 0, stream>>>(x, dW, db, h, N);

    const int ntiles = (E + EB - 1) / EB;
    edge_mfma_kernel<<<1024, 256, 0, stream>>>(
        ea, src, dst, Wt1, Wt2, fb1, fb2, h, out, E, ntiles);

    update_kernel<<<(N + NB - 1) / NB, 256, 0, stream>>>(
        x, uW1, ub1, uW2, ub2, out, N);
}

// Round 3
// 1158.350 us; speedup vs baseline: 1.9667x; 1.0397x over previous
//
#include <hip/hip_runtime.h>

#define H    128
#define RBF  50
#define K1   64    // stage-1 K padded 50 -> 64
#define EB   64    // edges per tile
#define NB   32

typedef _Float16 f16;
typedef _Float16 f16x8 __attribute__((ext_vector_type(8)));
typedef float    f32x4 __attribute__((ext_vector_type(4)));

// LDS row strides (f16 elems): +8 pad => 2-way bank aliasing (free), 16B-aligned rows
#define EA_LD 72    // 144 B
#define T_LD  136   // 272 B

__device__ __forceinline__ float silu_f(float a) {
    return a / (1.0f + __expf(-a));
}

// ---------------- CSR build: histogram -> scan -> scatter ----------------

__global__ __launch_bounds__(256) void hist_kernel(
    const int* __restrict__ dst, int* __restrict__ counts, int E)
{
    for (int i = blockIdx.x * 256 + threadIdx.x; i < E; i += gridDim.x * 256)
        atomicAdd(&counts[dst[i]], 1);
}

// single block, 1024 threads: cursor[i] = exclusive prefix sum of counts
__global__ __launch_bounds__(1024) void scan_kernel(
    const int* __restrict__ counts, int* __restrict__ cursor, int N)
{
    __shared__ int sums[1024];
    const int tid = threadIdx.x;
    const int C = (N + 1023) >> 10;
    const int begin = min(tid * C, N);
    const int end   = min(begin + C, N);
    int s = 0;
    for (int i = begin; i < end; ++i) s += counts[i];
    sums[tid] = s;
    __syncthreads();
    for (int off = 1; off < 1024; off <<= 1) {
        int v = 0;
        if (tid >= off) v = sums[tid - off];
        __syncthreads();
        sums[tid] += v;
        __syncthreads();
    }
    int run = (tid > 0) ? sums[tid - 1] : 0;
    for (int i = begin; i < end; ++i) { cursor[i] = run; run += counts[i]; }
}

__global__ __launch_bounds__(256) void scatter_kernel(
    const int* __restrict__ dst, int* __restrict__ cursor,
    int* __restrict__ perm, int E)
{
    for (int i = blockIdx.x * 256 + threadIdx.x; i < E; i += gridDim.x * 256) {
        int pos = atomicAdd(&cursor[dst[i]], 1);
        perm[pos] = i;
    }
}

// ---------------- weight convert + h ----------------

// Wt1[n][k] = fW1[k][n] (f16, k in [0,64), zero-padded); Wt2[n][k] = fW2[k][n]
__global__ __launch_bounds__(256) void convert_weights_kernel(
    const float* __restrict__ fW1, const float* __restrict__ fW2,
    f16* __restrict__ Wt1, f16* __restrict__ Wt2)
{
    int i = blockIdx.x * 256 + threadIdx.x;
    if (i < H * K1) {
        int n = i >> 6, k = i & (K1 - 1);
        Wt1[i] = (k < RBF) ? (f16)fW1[k * H + n] : (f16)0.f;
    }
    int j = i - H * K1;
    if (j >= 0 && j < H * H) {
        int n = j >> 7, k = j & (H - 1);
        Wt2[j] = (f16)fW2[k * H + n];
    }
}

// h = x @ dW + db   [N,128] fp32 compute, f16 store
__global__ __launch_bounds__(256) void compute_h_kernel(
    const float* __restrict__ x, const float* __restrict__ dW,
    const float* __restrict__ db, f16* __restrict__ h, int N)
{
    __shared__ float xs[NB][H];
    const int tid = threadIdx.x;
    const int n0  = blockIdx.x * NB;

    for (int idx = tid; idx < NB * H; idx += 256) {
        int r = idx >> 7, c = idx & (H - 1);
        int n = n0 + r;
        xs[r][c] = (n < N) ? x[(size_t)n * H + c] : 0.f;
    }
    __syncthreads();

    const int j  = tid & (H - 1);
    const int rb = (tid >> 7) * 16;

    float acc[16];
    const float b = db[j];
#pragma unroll
    for (int r = 0; r < 16; ++r) acc[r] = b;

    for (int kq = 0; kq < H / 4; ++kq) {
        const int k = kq * 4;
        const float w0 = dW[(k + 0) * H + j];
        const float w1 = dW[(k + 1) * H + j];
        const float w2 = dW[(k + 2) * H + j];
        const float w3 = dW[(k + 3) * H + j];
#pragma unroll
        for (int r = 0; r < 16; ++r) {
            const float4 v = *(const float4*)&xs[rb + r][k];
            acc[r] = fmaf(v.x, w0, fmaf(v.y, w1, fmaf(v.z, w2, fmaf(v.w, w3, acc[r]))));
        }
    }
#pragma unroll
    for (int r = 0; r < 16; ++r) {
        int n = n0 + rb + r;
        if (n < N) h[(size_t)n * H + j] = (f16)acc[r];
    }
}

// ---------------- fused edge kernel on dst-sorted permutation ----------------
// filters = silu(ea[perm]@W1+b1)@W2+b2 ; msg = h[src]*filters -> LDS ;
// segmented reduce over sorted dst -> few atomics per tile.
__global__ __launch_bounds__(256, 4) void edge_mfma_kernel(
    const float* __restrict__ ea,
    const int* __restrict__ src_idx, const int* __restrict__ dst_idx,
    const int* __restrict__ perm,
    const f16* __restrict__ Wt1, const f16* __restrict__ Wt2,
    const float* __restrict__ fb1, const float* __restrict__ fb2,
    const f16* __restrict__ h, float* __restrict__ out, int E, int ntiles)
{
    union SharedU {
        struct { f16 ea[EB][EA_LD]; f16 t[EB][T_LD]; } s;
        float msg[EB][H];          // overlays ea+t after stage-2 reads complete
    };
    __shared__ __align__(16) SharedU u;
    __shared__ int src_s[EB];
    __shared__ int dst_s[EB];

    const int tid  = threadIdx.x;
    const int lane = tid & 63;
    const int wv   = tid >> 6;        // 4 waves
    const int wr   = (wv >> 1) * 32;  // wave row base: 0 or 32
    const int wc   = (wv & 1) * 64;   // wave col base: 0 or 64
    const int fr   = lane & 15;       // frag row (A) / col (B,C)
    const int qw   = lane >> 4;       // quarter-wave
    const int kb   = qw * 8;          // frag k-block base

    // ---- persistent B fragments (loaded once per block) ----
    f16x8 B1[4][2];
    f16x8 B2[4][4];
    float b1v[4], b2v[4];
#pragma unroll
    for (int ct = 0; ct < 4; ++ct) {
        const int col = wc + ct * 16 + fr;
#pragma unroll
        for (int ks = 0; ks < 2; ++ks)
            B1[ct][ks] = *(const f16x8*)&Wt1[col * K1 + ks * 32 + kb];
#pragma unroll
        for (int ks = 0; ks < 4; ++ks)
            B2[ct][ks] = *(const f16x8*)&Wt2[col * H + ks * 32 + kb];
        b1v[ct] = fb1[col];
        b2v[ct] = fb2[col];
    }

    for (int t = blockIdx.x; t < ntiles; t += gridDim.x) {
        const int e0 = t * EB;
        __syncthreads();   // prev tile's msg reads done before restaging

        // ---- stage permuted ea tile fp32 -> f16 (zero-pad k 50..63, OOB rows) ----
        for (int idx = tid; idx < EB * 32; idx += 256) {
            int r = idx >> 5, p = (idx & 31) * 2;
            int pe = e0 + r;
            int e = (pe < E) ? perm[pe] : -1;
            f16 a = (f16)0.f, b = (f16)0.f;
            if (e >= 0 && p < RBF) {
                const float2 v = *(const float2*)&ea[(size_t)e * RBF + p];
                a = (f16)v.x; b = (f16)v.y;
            }
            u.s.ea[r][p]     = a;
            u.s.ea[r][p + 1] = b;
        }
        if (tid < EB) {
            int pe = e0 + tid;
            int e = (pe < E) ? perm[pe] : -1;
            src_s[tid] = (e >= 0) ? src_idx[e] : 0;
            dst_s[tid] = (e >= 0) ? dst_idx[e] : -1;
        }
        __syncthreads();

        // ---- stage 1: t = ea @ W1 + b1 ----
        f32x4 acc[2][4];
#pragma unroll
        for (int rt = 0; rt < 2; ++rt)
#pragma unroll
            for (int ct = 0; ct < 4; ++ct)
                acc[rt][ct] = (f32x4){b1v[ct], b1v[ct], b1v[ct], b1v[ct]};

#pragma unroll
        for (int ks = 0; ks < 2; ++ks) {
            const f16x8 A0 = *(const f16x8*)&u.s.ea[wr + fr][ks * 32 + kb];
            const f16x8 A1 = *(const f16x8*)&u.s.ea[wr + 16 + fr][ks * 32 + kb];
#pragma unroll
            for (int ct = 0; ct < 4; ++ct) {
                acc[0][ct] = __builtin_amdgcn_mfma_f32_16x16x32_f16(A0, B1[ct][ks], acc[0][ct], 0, 0, 0);
                acc[1][ct] = __builtin_amdgcn_mfma_f32_16x16x32_f16(A1, B1[ct][ks], acc[1][ct], 0, 0, 0);
            }
        }

        // ---- silu -> t (f16) ----
#pragma unroll
        for (int rt = 0; rt < 2; ++rt)
#pragma unroll
            for (int ct = 0; ct < 4; ++ct)
#pragma unroll
                for (int m = 0; m < 4; ++m) {
                    const int row = wr + rt * 16 + qw * 4 + m;
                    const int col = wc + ct * 16 + fr;
                    u.s.t[row][col] = (f16)silu_f(acc[rt][ct][m]);
                }
        __syncthreads();

        // ---- stage 2: filters = t @ W2 + b2 ----
        f32x4 acc2[2][4];
#pragma unroll
        for (int rt = 0; rt < 2; ++rt)
#pragma unroll
            for (int ct = 0; ct < 4; ++ct)
                acc2[rt][ct] = (f32x4){b2v[ct], b2v[ct], b2v[ct], b2v[ct]};

#pragma unroll
        for (int ks = 0; ks < 4; ++ks) {
            const f16x8 A0 = *(const f16x8*)&u.s.t[wr + fr][ks * 32 + kb];
            const f16x8 A1 = *(const f16x8*)&u.s.t[wr + 16 + fr][ks * 32 + kb];
#pragma unroll
            for (int ct = 0; ct < 4; ++ct) {
                acc2[0][ct] = __builtin_amdgcn_mfma_f32_16x16x32_f16(A0, B2[ct][ks], acc2[0][ct], 0, 0, 0);
                acc2[1][ct] = __builtin_amdgcn_mfma_f32_16x16x32_f16(A1, B2[ct][ks], acc2[1][ct], 0, 0, 0);
            }
        }
        __syncthreads();   // all t reads done before msg overlays it

        // ---- msg = h[src] * filters -> LDS (f32) ----
#pragma unroll
        for (int rt = 0; rt < 2; ++rt)
#pragma unroll
            for (int ct = 0; ct < 4; ++ct)
#pragma unroll
                for (int m = 0; m < 4; ++m) {
                    const int er  = wr + rt * 16 + qw * 4 + m;
                    const int col = wc + ct * 16 + fr;
                    const int s2  = src_s[er];
                    u.msg[er][col] = (float)h[(size_t)s2 * H + col] * acc2[rt][ct][m];
                }
        __syncthreads();

        // ---- segmented reduce over sorted dst rows -> atomics at boundaries ----
        {
            const int col = tid & 127;
            const int r0  = (tid >> 7) * 32;
            float accv = 0.f;
            int cur = dst_s[r0];
#pragma unroll
            for (int rr = 0; rr < 32; ++rr) {
                const int r = r0 + rr;
                const int d = dst_s[r];
                const float v = u.msg[r][col];
                if (d != cur) {
                    if (cur >= 0) unsafeAtomicAdd(&out[(size_t)cur * H + col], accv);
                    cur = d; accv = 0.f;
                }
                if (d >= 0) accv += v;
            }
            if (cur >= 0) unsafeAtomicAdd(&out[(size_t)cur * H + col], accv);
        }
    }
}

// out = x + silu(agg@uW1+ub1)@uW2+ub2 ; agg lives in `out` on entry
__global__ __launch_bounds__(256) void update_kernel(
    const float* __restrict__ x,
    const float* __restrict__ uW1, const float* __restrict__ ub1,
    const float* __restrict__ uW2, const float* __restrict__ ub2,
    float* __restrict__ out, int N)
{
    __shared__ float as[NB][H];
    __shared__ float ts[NB][H];
    const int tid = threadIdx.x;
    const int n0  = blockIdx.x * NB;

    for (int idx = tid; idx < NB * H; idx += 256) {
        int r = idx >> 7, c = idx & (H - 1);
        int n = n0 + r;
        as[r][c] = (n < N) ? out[(size_t)n * H + c] : 0.f;
    }
    __syncthreads();

    const int j  = tid & (H - 1);
    const int rb = (tid >> 7) * 16;

    float acc[16];
    {
        const float b1 = ub1[j];
#pragma unroll
        for (int r = 0; r < 16; ++r) acc[r] = b1;
    }
    for (int kq = 0; kq < H / 4; ++kq) {
        const int k = kq * 4;
        const float w0 = uW1[(k + 0) * H + j];
        const float w1 = uW1[(k + 1) * H + j];
        const float w2 = uW1[(k + 2) * H + j];
        const float w3 = uW1[(k + 3) * H + j];
#pragma unroll
        for (int r = 0; r < 16; ++r) {
            const float4 v = *(const float4*)&as[rb + r][k];
            acc[r] = fmaf(v.x, w0, fmaf(v.y, w1, fmaf(v.z, w2, fmaf(v.w, w3, acc[r]))));
        }
    }
#pragma unroll
    for (int r = 0; r < 16; ++r) ts[rb + r][j] = silu_f(acc[r]);
    __syncthreads();

    {
        const float b2 = ub2[j];
#pragma unroll
        for (int r = 0; r < 16; ++r) acc[r] = b2;
    }
    for (int kq = 0; kq < H / 4; ++kq) {
        const int k = kq * 4;
        const float w0 = uW2[(k + 0) * H + j];
        const float w1 = uW2[(k + 1) * H + j];
        const float w2 = uW2[(k + 2) * H + j];
        const float w3 = uW2[(k + 3) * H + j];
#pragma unroll
        for (int r = 0; r < 16; ++r) {
            const float4 v = *(const float4*)&ts[rb + r][k];
            acc[r] = fmaf(v.x, w0, fmaf(v.y, w1, fmaf(v.z, w2, fmaf(v.w, w3, acc[r]))));
        }
    }
#pragma unroll
    for (int r = 0; r < 16; ++r) {
        int n = n0 + rb + r;
        if (n < N) out[(size_t)n * H + j] = x[(size_t)n * H + j] + acc[r];
    }
}

extern "C" void kernel_launch(void* const* d_in, const int* in_sizes, int n_in,
                              void* d_out, int out_size, void* d_ws, size_t ws_size,
                              hipStream_t stream) {
    const float* x   = (const float*)d_in[0];
    const int*   ei  = (const int*)  d_in[1];
    const float* ea  = (const float*)d_in[2];
    const float* fW1 = (const float*)d_in[3];
    const float* fb1 = (const float*)d_in[4];
    const float* fW2 = (const float*)d_in[5];
    const float* fb2 = (const float*)d_in[6];
    const float* dW  = (const float*)d_in[7];
    const float* db  = (const float*)d_in[8];
    const float* uW1 = (const float*)d_in[9];
    const float* ub1 = (const float*)d_in[10];
    const float* uW2 = (const float*)d_in[11];
    const float* ub2 = (const float*)d_in[12];

    float* out = (float*)d_out;

    const int N = in_sizes[0] / H;
    const int E = in_sizes[1] / 2;
    const int* src = ei;
    const int* dst = ei + E;

    // workspace layout (~19.8 MB; 25.6 MB proven available in R1)
    char* ws = (char*)d_ws;
    size_t off = 0;
    auto alloc = [&](size_t bytes) { void* p = ws + off; off = (off + bytes + 255) & ~(size_t)255; return p; };
    f16* h      = (f16*)alloc((size_t)N * H * sizeof(f16));
    f16* Wt1    = (f16*)alloc((size_t)H * K1 * sizeof(f16));
    f16* Wt2    = (f16*)alloc((size_t)H * H * sizeof(f16));
    int* counts = (int*)alloc((size_t)N * sizeof(int));
    int* cursor = (int*)alloc((size_t)N * sizeof(int));
    int* perm   = (int*)alloc((size_t)E * sizeof(int));

    hipMemsetAsync(out, 0, (size_t)N * H * sizeof(float), stream);
    hipMemsetAsync(counts, 0, (size_t)N * sizeof(int), stream);

    convert_weights_kernel<<<(H * K1 + H * H + 255) / 256, 256, 0, stream>>>(fW1, fW2, Wt1, Wt2);
    compute_h_kernel<<<(N + NB - 1) / NB, 256, 0, stream>>>(x, dW, db, h, N);

    hist_kernel<<<1024, 256, 0, stream>>>(dst, counts, E);
    scan_kernel<<<1, 1024, 0, stream>>>(counts, cursor, N);
    scatter_kernel<<<1024, 256, 0, stream>>>(dst, cursor, perm, E);

    const int ntiles = (E + EB - 1) / EB;
    const int nblk = (ntiles < 4096) ? ntiles : 4096;
    edge_mfma_kernel<<<nblk, 256, 0, stream>>>(
        ea, src, dst, perm, Wt1, Wt2, fb1, fb2, h, out, E, ntiles);

    update_kernel<<<(N + NB - 1) / NB, 256, 0, stream>>>(
        x, uW1, ub1, uW2, ub2, out, N);
}

// Round 4
// 1107.925 us; speedup vs baseline: 2.0562x; 1.0455x over previous
//
#include <hip/hip_runtime.h>

#define H    128
#define RBF  50
#define K1   64     // stage-1 K padded 50 -> 64
#define EB   64     // edges per tile
#define NB   32
#define ROWF 96     // packed ea16 row stride (f16 units) = 192B = 3 sectors: [0,64) ea, [64]=src int, [66]=dst int
#define NBLK 1024   // edge blocks (exactly one resident generation at 4 blocks/CU)

typedef _Float16 f16;
typedef _Float16 f16x8 __attribute__((ext_vector_type(8)));
typedef float    f32x4 __attribute__((ext_vector_type(4)));

// LDS strides (f16 elems) tuned for conflict-light ds_read_b128
#define EA_LD    104   // 208B: fr*208 % 128 walks all 8 bank-quads -> 2-way (free)
#define T_LD     136   // 272B: 272 % 128 == 16 -> perfect 16B tiling
#define EA_LD_FB 72    // fallback kernel (R3 layout)
#define T_LD_FB  136

__device__ __forceinline__ float silu_f(float a) {
    return a / (1.0f + __expf(-a));
}

// ---------------- CSR build ----------------

__global__ __launch_bounds__(256) void hist_kernel(
    const int* __restrict__ dst, int* __restrict__ counts, int E)
{
    for (int i = blockIdx.x * 256 + threadIdx.x; i < E; i += gridDim.x * 256)
        atomicAdd(&counts[dst[i]], 1);
}

// 3-phase exclusive scan: counts[N] -> ofs[N]
__global__ __launch_bounds__(256) void scan1_kernel(
    const int* __restrict__ counts, int* __restrict__ ofs, int* __restrict__ bsum, int N)
{
    __shared__ int s[256];
    const int t = threadIdx.x;
    const int g = blockIdx.x * 256 + t;
    int v = (g < N) ? counts[g] : 0;
    s[t] = v; __syncthreads();
    for (int off = 1; off < 256; off <<= 1) {
        int u = 0; if (t >= off) u = s[t - off];
        __syncthreads(); s[t] += u; __syncthreads();
    }
    if (g < N) ofs[g] = s[t] - v;
    if (t == 255) bsum[blockIdx.x] = s[255];
}
__global__ __launch_bounds__(256) void scan2_kernel(int* __restrict__ bsum, int nb)
{
    __shared__ int s[256];
    const int t = threadIdx.x;
    int v = (t < nb) ? bsum[t] : 0;
    s[t] = v; __syncthreads();
    for (int off = 1; off < 256; off <<= 1) {
        int u = 0; if (t >= off) u = s[t - off];
        __syncthreads(); s[t] += u; __syncthreads();
    }
    if (t < nb) bsum[t] = s[t] - v;
}
__global__ __launch_bounds__(256) void scan3_kernel(
    int* __restrict__ ofs, const int* __restrict__ bsum, int N)
{
    int g = blockIdx.x * 256 + threadIdx.x;
    if (g < N) ofs[g] += bsum[blockIdx.x];
}

// block ranges cut at node boundaries near b*E/B edges
__global__ __launch_bounds__(256) void ranges_kernel(
    const int* __restrict__ ofs, int* __restrict__ nstart, int* __restrict__ estart,
    int N, int E, int B)
{
    int b = blockIdx.x * 256 + threadIdx.x;
    if (b > B) return;
    if (b == B) { nstart[B] = N; estart[B] = E; return; }
    long long cb = (long long)b * E / B;
    int lo = 0, hi = N;
    while (lo < hi) {
        int mid = (lo + hi) >> 1;
        int val = (mid < N) ? ofs[mid] : E;
        if (val < (int)cb) lo = mid + 1; else hi = mid;
    }
    nstart[b] = lo;
    estart[b] = (lo < N) ? ofs[lo] : E;
}

// full path: rank[e] = permuted position   (destroys ofs)
__global__ __launch_bounds__(256) void scatter_rank_kernel(
    const int* __restrict__ dst, int* __restrict__ cursor, int* __restrict__ rank, int E)
{
    for (int i = blockIdx.x * 256 + threadIdx.x; i < E; i += gridDim.x * 256)
        rank[i] = atomicAdd(&cursor[dst[i]], 1);
}
// fallback path: perm[pos] = e
__global__ __launch_bounds__(256) void scatter_perm_kernel(
    const int* __restrict__ dst, int* __restrict__ cursor, int* __restrict__ perm, int E)
{
    for (int i = blockIdx.x * 256 + threadIdx.x; i < E; i += gridDim.x * 256) {
        int pos = atomicAdd(&cursor[dst[i]], 1);
        perm[pos] = i;
    }
}

// sequential read ea f32 -> packed f16 rows written at rank[e]
__global__ __launch_bounds__(256) void permute_ea_kernel(
    const float* __restrict__ ea, const int* __restrict__ src_idx,
    const int* __restrict__ dst_idx, const int* __restrict__ rank,
    f16* __restrict__ ea16, int E, int ntiles)
{
    __shared__ f16 tile[EB][ROWF];
    __shared__ int rk[EB];
    const int tid = threadIdx.x;
    for (int t = blockIdx.x; t < ntiles; t += gridDim.x) {
        const int e0 = t * EB;
        __syncthreads();
        for (int idx = tid; idx < EB * RBF; idx += 256) {
            int r = idx / RBF, c = idx % RBF;
            int e = e0 + r;
            tile[r][c] = (e < E) ? (f16)ea[(size_t)e * RBF + c] : (f16)0.f;
        }
        if (tid < EB) {
            int e = e0 + tid;
            for (int c = RBF; c < K1; ++c) tile[tid][c] = (f16)0.f;
            *(int*)&tile[tid][64] = (e < E) ? src_idx[e] : 0;
            *(int*)&tile[tid][66] = (e < E) ? dst_idx[e] : 0;
            rk[tid] = (e < E) ? rank[e] : -1;
        }
        __syncthreads();
        for (int idx = tid; idx < EB * 12; idx += 256) {
            int r = idx / 12, q = idx % 12;
            int p = rk[r];
            if (p >= 0)
                *(f16x8*)&ea16[(size_t)p * ROWF + q * 8] = *(const f16x8*)&tile[r][q * 8];
        }
    }
}

// ---------------- weight convert + h ----------------

__global__ __launch_bounds__(256) void convert_weights_kernel(
    const float* __restrict__ fW1, const float* __restrict__ fW2,
    f16* __restrict__ Wt1, f16* __restrict__ Wt2)
{
    int i = blockIdx.x * 256 + threadIdx.x;
    if (i < H * K1) {
        int n = i >> 6, k = i & (K1 - 1);
        Wt1[i] = (k < RBF) ? (f16)fW1[k * H + n] : (f16)0.f;
    }
    int j = i - H * K1;
    if (j >= 0 && j < H * H) {
        int n = j >> 7, k = j & (H - 1);
        Wt2[j] = (f16)fW2[k * H + n];
    }
}

__global__ __launch_bounds__(256) void compute_h_kernel(
    const float* __restrict__ x, const float* __restrict__ dW,
    const float* __restrict__ db, f16* __restrict__ h, int N)
{
    __shared__ float xs[NB][H];
    const int tid = threadIdx.x;
    const int n0  = blockIdx.x * NB;
    for (int idx = tid; idx < NB * H; idx += 256) {
        int r = idx >> 7, c = idx & (H - 1);
        int n = n0 + r;
        xs[r][c] = (n < N) ? x[(size_t)n * H + c] : 0.f;
    }
    __syncthreads();
    const int j  = tid & (H - 1);
    const int rb = (tid >> 7) * 16;
    float acc[16];
    const float b = db[j];
#pragma unroll
    for (int r = 0; r < 16; ++r) acc[r] = b;
    for (int kq = 0; kq < H / 4; ++kq) {
        const int k = kq * 4;
        const float w0 = dW[(k + 0) * H + j];
        const float w1 = dW[(k + 1) * H + j];
        const float w2 = dW[(k + 2) * H + j];
        const float w3 = dW[(k + 3) * H + j];
#pragma unroll
        for (int r = 0; r < 16; ++r) {
            const float4 v = *(const float4*)&xs[rb + r][k];
            acc[r] = fmaf(v.x, w0, fmaf(v.y, w1, fmaf(v.z, w2, fmaf(v.w, w3, acc[r]))));
        }
    }
#pragma unroll
    for (int r = 0; r < 16; ++r) {
        int n = n0 + rb + r;
        if (n < N) h[(size_t)n * H + j] = (f16)acc[r];
    }
}

// ---------------- FULL PATH edge kernel: CSR block ownership, zero atomics ----------------
__global__ __launch_bounds__(256, 4) void edge_grouped_kernel(
    const f16* __restrict__ ea16,
    const f16* __restrict__ Wt1, const f16* __restrict__ Wt2,
    const float* __restrict__ fb1, const float* __restrict__ fb2,
    const f16* __restrict__ h, float* __restrict__ out,
    const int* __restrict__ nstart, const int* __restrict__ estart)
{
    union SharedU {
        struct { f16 ea[EB][EA_LD]; f16 t[EB][T_LD]; } s;
        float msg[EB][H];
    };
    __shared__ __align__(16) SharedU u;
    __shared__ int src_s[EB];
    __shared__ int dst_s[EB];

    const int tid  = threadIdx.x;
    const int lane = tid & 63;
    const int wv   = tid >> 6;
    const int wr   = (wv >> 1) * 32;
    const int wc   = (wv & 1) * 64;
    const int fr   = lane & 15;
    const int qw   = lane >> 4;
    const int kb   = qw * 8;

    f16x8 B1[4][2];
    f16x8 B2[4][4];
    float b1v[4], b2v[4];
#pragma unroll
    for (int ct = 0; ct < 4; ++ct) {
        const int col = wc + ct * 16 + fr;
#pragma unroll
        for (int ks = 0; ks < 2; ++ks)
            B1[ct][ks] = *(const f16x8*)&Wt1[col * K1 + ks * 32 + kb];
#pragma unroll
        for (int ks = 0; ks < 4; ++ks)
            B2[ct][ks] = *(const f16x8*)&Wt2[col * H + ks * 32 + kb];
        b1v[ct] = fb1[col];
        b2v[ct] = fb2[col];
    }

    const int ns = nstart[blockIdx.x], ne = nstart[blockIdx.x + 1];
    const int e0 = estart[blockIdx.x], e1 = estart[blockIdx.x + 1];

    // reducer state (threads tid<128): running per-dst sum in registers
    const int col128 = tid & 127;
    int   curdst = ns;
    float accv   = 0.f;

    for (int tb = e0; tb < e1; tb += EB) {
        const int nrows = min(EB, e1 - tb);
        __syncthreads();   // prev tile's msg reads done

        // stage packed rows (fully sequential)
        for (int idx = tid; idx < EB * 12; idx += 256) {
            int r = idx / 12, q = idx % 12;
            f16x8 v = {};
            if (r < nrows) v = *(const f16x8*)&ea16[(size_t)(tb + r) * ROWF + q * 8];
            *(f16x8*)&u.s.ea[r][q * 8] = v;
        }
        if (tid < EB) {
            int r = tid;
            if (r < nrows) {
                src_s[r] = *(const int*)&ea16[(size_t)(tb + r) * ROWF + 64];
                dst_s[r] = *(const int*)&ea16[(size_t)(tb + r) * ROWF + 66];
            } else { src_s[r] = 0; dst_s[r] = ne; }   // sentinel
        }
        __syncthreads();

        // stage 1: t = ea @ W1 + b1
        f32x4 acc[2][4];
#pragma unroll
        for (int rt = 0; rt < 2; ++rt)
#pragma unroll
            for (int ct = 0; ct < 4; ++ct)
                acc[rt][ct] = (f32x4){b1v[ct], b1v[ct], b1v[ct], b1v[ct]};
#pragma unroll
        for (int ks = 0; ks < 2; ++ks) {
            const f16x8 A0 = *(const f16x8*)&u.s.ea[wr + fr][ks * 32 + kb];
            const f16x8 A1 = *(const f16x8*)&u.s.ea[wr + 16 + fr][ks * 32 + kb];
#pragma unroll
            for (int ct = 0; ct < 4; ++ct) {
                acc[0][ct] = __builtin_amdgcn_mfma_f32_16x16x32_f16(A0, B1[ct][ks], acc[0][ct], 0, 0, 0);
                acc[1][ct] = __builtin_amdgcn_mfma_f32_16x16x32_f16(A1, B1[ct][ks], acc[1][ct], 0, 0, 0);
            }
        }

        // silu -> t (f16)
#pragma unroll
        for (int rt = 0; rt < 2; ++rt)
#pragma unroll
            for (int ct = 0; ct < 4; ++ct)
#pragma unroll
                for (int m = 0; m < 4; ++m) {
                    const int row = wr + rt * 16 + qw * 4 + m;
                    const int c   = wc + ct * 16 + fr;
                    u.s.t[row][c] = (f16)silu_f(acc[rt][ct][m]);
                }
        __syncthreads();

        // stage 2: filters = t @ W2 + b2
        f32x4 acc2[2][4];
#pragma unroll
        for (int rt = 0; rt < 2; ++rt)
#pragma unroll
            for (int ct = 0; ct < 4; ++ct)
                acc2[rt][ct] = (f32x4){b2v[ct], b2v[ct], b2v[ct], b2v[ct]};
#pragma unroll
        for (int ks = 0; ks < 4; ++ks) {
            const f16x8 A0 = *(const f16x8*)&u.s.t[wr + fr][ks * 32 + kb];
            const f16x8 A1 = *(const f16x8*)&u.s.t[wr + 16 + fr][ks * 32 + kb];
#pragma unroll
            for (int ct = 0; ct < 4; ++ct) {
                acc2[0][ct] = __builtin_amdgcn_mfma_f32_16x16x32_f16(A0, B2[ct][ks], acc2[0][ct], 0, 0, 0);
                acc2[1][ct] = __builtin_amdgcn_mfma_f32_16x16x32_f16(A1, B2[ct][ks], acc2[1][ct], 0, 0, 0);
            }
        }
        __syncthreads();   // all t reads done before msg overlays

        // msg = h[src] * filters -> LDS (f32)
#pragma unroll
        for (int rt = 0; rt < 2; ++rt)
#pragma unroll
            for (int ct = 0; ct < 4; ++ct)
#pragma unroll
                for (int m = 0; m < 4; ++m) {
                    const int er = wr + rt * 16 + qw * 4 + m;
                    const int c  = wc + ct * 16 + fr;
                    const int s2 = src_s[er];
                    u.msg[er][c] = (float)h[(size_t)s2 * H + c] * acc2[rt][ct][m];
                }
        __syncthreads();

        // sequential segmented reduce: this block owns [ns,ne) exclusively -> plain stores
        if (tid < 128) {
            for (int r = 0; r < EB; ++r) {
                const int d = dst_s[r];
                if (d != curdst) {
                    out[(size_t)curdst * H + col128] = accv;
                    for (int n = curdst + 1; n < d; ++n) out[(size_t)n * H + col128] = 0.f;
                    curdst = d; accv = 0.f;
                }
                if (d < ne) accv += u.msg[r][col128];
            }
        }
    }
    if (tid < 128 && curdst < ne) {
        out[(size_t)curdst * H + col128] = accv;
        for (int n = curdst + 1; n < ne; ++n) out[(size_t)n * H + col128] = 0.f;
    }
}

// ---------------- FALLBACK edge kernel (R3, proven) ----------------
__global__ __launch_bounds__(256, 4) void edge_perm_kernel(
    const float* __restrict__ ea,
    const int* __restrict__ src_idx, const int* __restrict__ dst_idx,
    const int* __restrict__ perm,
    const f16* __restrict__ Wt1, const f16* __restrict__ Wt2,
    const float* __restrict__ fb1, const float* __restrict__ fb2,
    const f16* __restrict__ h, float* __restrict__ out, int E, int ntiles)
{
    union SharedU {
        struct { f16 ea[EB][EA_LD_FB]; f16 t[EB][T_LD_FB]; } s;
        float msg[EB][H];
    };
    __shared__ __align__(16) SharedU u;
    __shared__ int src_s[EB];
    __shared__ int dst_s[EB];

    const int tid  = threadIdx.x;
    const int lane = tid & 63;
    const int wv   = tid >> 6;
    const int wr   = (wv >> 1) * 32;
    const int wc   = (wv & 1) * 64;
    const int fr   = lane & 15;
    const int qw   = lane >> 4;
    const int kb   = qw * 8;

    f16x8 B1[4][2];
    f16x8 B2[4][4];
    float b1v[4], b2v[4];
#pragma unroll
    for (int ct = 0; ct < 4; ++ct) {
        const int col = wc + ct * 16 + fr;
#pragma unroll
        for (int ks = 0; ks < 2; ++ks)
            B1[ct][ks] = *(const f16x8*)&Wt1[col * K1 + ks * 32 + kb];
#pragma unroll
        for (int ks = 0; ks < 4; ++ks)
            B2[ct][ks] = *(const f16x8*)&Wt2[col * H + ks * 32 + kb];
        b1v[ct] = fb1[col];
        b2v[ct] = fb2[col];
    }

    for (int t = blockIdx.x; t < ntiles; t += gridDim.x) {
        const int e0 = t * EB;
        __syncthreads();
        for (int idx = tid; idx < EB * 32; idx += 256) {
            int r = idx >> 5, p = (idx & 31) * 2;
            int pe = e0 + r;
            int e = (pe < E) ? perm[pe] : -1;
            f16 a = (f16)0.f, b = (f16)0.f;
            if (e >= 0 && p < RBF) {
                const float2 v = *(const float2*)&ea[(size_t)e * RBF + p];
                a = (f16)v.x; b = (f16)v.y;
            }
            u.s.ea[r][p]     = a;
            u.s.ea[r][p + 1] = b;
        }
        if (tid < EB) {
            int pe = e0 + tid;
            int e = (pe < E) ? perm[pe] : -1;
            src_s[tid] = (e >= 0) ? src_idx[e] : 0;
            dst_s[tid] = (e >= 0) ? dst_idx[e] : -1;
        }
        __syncthreads();

        f32x4 acc[2][4];
#pragma unroll
        for (int rt = 0; rt < 2; ++rt)
#pragma unroll
            for (int ct = 0; ct < 4; ++ct)
                acc[rt][ct] = (f32x4){b1v[ct], b1v[ct], b1v[ct], b1v[ct]};
#pragma unroll
        for (int ks = 0; ks < 2; ++ks) {
            const f16x8 A0 = *(const f16x8*)&u.s.ea[wr + fr][ks * 32 + kb];
            const f16x8 A1 = *(const f16x8*)&u.s.ea[wr + 16 + fr][ks * 32 + kb];
#pragma unroll
            for (int ct = 0; ct < 4; ++ct) {
                acc[0][ct] = __builtin_amdgcn_mfma_f32_16x16x32_f16(A0, B1[ct][ks], acc[0][ct], 0, 0, 0);
                acc[1][ct] = __builtin_amdgcn_mfma_f32_16x16x32_f16(A1, B1[ct][ks], acc[1][ct], 0, 0, 0);
            }
        }
#pragma unroll
        for (int rt = 0; rt < 2; ++rt)
#pragma unroll
            for (int ct = 0; ct < 4; ++ct)
#pragma unroll
                for (int m = 0; m < 4; ++m) {
                    const int row = wr + rt * 16 + qw * 4 + m;
                    const int c   = wc + ct * 16 + fr;
                    u.s.t[row][c] = (f16)silu_f(acc[rt][ct][m]);
                }
        __syncthreads();

        f32x4 acc2[2][4];
#pragma unroll
        for (int rt = 0; rt < 2; ++rt)
#pragma unroll
            for (int ct = 0; ct < 4; ++ct)
                acc2[rt][ct] = (f32x4){b2v[ct], b2v[ct], b2v[ct], b2v[ct]};
#pragma unroll
        for (int ks = 0; ks < 4; ++ks) {
            const f16x8 A0 = *(const f16x8*)&u.s.t[wr + fr][ks * 32 + kb];
            const f16x8 A1 = *(const f16x8*)&u.s.t[wr + 16 + fr][ks * 32 + kb];
#pragma unroll
            for (int ct = 0; ct < 4; ++ct) {
                acc2[0][ct] = __builtin_amdgcn_mfma_f32_16x16x32_f16(A0, B2[ct][ks], acc2[0][ct], 0, 0, 0);
                acc2[1][ct] = __builtin_amdgcn_mfma_f32_16x16x32_f16(A1, B2[ct][ks], acc2[1][ct], 0, 0, 0);
            }
        }
        __syncthreads();
#pragma unroll
        for (int rt = 0; rt < 2; ++rt)
#pragma unroll
            for (int ct = 0; ct < 4; ++ct)
#pragma unroll
                for (int m = 0; m < 4; ++m) {
                    const int er = wr + rt * 16 + qw * 4 + m;
                    const int c  = wc + ct * 16 + fr;
                    const int s2 = src_s[er];
                    u.msg[er][c] = (float)h[(size_t)s2 * H + c] * acc2[rt][ct][m];
                }
        __syncthreads();
        {
            const int c  = tid & 127;
            const int r0 = (tid >> 7) * 32;
            float av = 0.f;
            int cur = dst_s[r0];
#pragma unroll
            for (int rr = 0; rr < 32; ++rr) {
                const int r = r0 + rr;
                const int d = dst_s[r];
                const float v = u.msg[r][c];
                if (d != cur) {
                    if (cur >= 0) unsafeAtomicAdd(&out[(size_t)cur * H + c], av);
                    cur = d; av = 0.f;
                }
                if (d >= 0) av += v;
            }
            if (cur >= 0) unsafeAtomicAdd(&out[(size_t)cur * H + c], av);
        }
    }
}

// out = x + silu(agg@uW1+ub1)@uW2+ub2 ; agg lives in `out` on entry
__global__ __launch_bounds__(256) void update_kernel(
    const float* __restrict__ x,
    const float* __restrict__ uW1, const float* __restrict__ ub1,
    const float* __restrict__ uW2, const float* __restrict__ ub2,
    float* __restrict__ out, int N)
{
    __shared__ float as[NB][H];
    __shared__ float ts[NB][H];
    const int tid = threadIdx.x;
    const int n0  = blockIdx.x * NB;
    for (int idx = tid; idx < NB * H; idx += 256) {
        int r = idx >> 7, c = idx & (H - 1);
        int n = n0 + r;
        as[r][c] = (n < N) ? out[(size_t)n * H + c] : 0.f;
    }
    __syncthreads();
    const int j  = tid & (H - 1);
    const int rb = (tid >> 7) * 16;
    float acc[16];
    {
        const float b1 = ub1[j];
#pragma unroll
        for (int r = 0; r < 16; ++r) acc[r] = b1;
    }
    for (int kq = 0; kq < H / 4; ++kq) {
        const int k = kq * 4;
        const float w0 = uW1[(k + 0) * H + j];
        const float w1 = uW1[(k + 1) * H + j];
        const float w2 = uW1[(k + 2) * H + j];
        const float w3 = uW1[(k + 3) * H + j];
#pragma unroll
        for (int r = 0; r < 16; ++r) {
            const float4 v = *(const float4*)&as[rb + r][k];
            acc[r] = fmaf(v.x, w0, fmaf(v.y, w1, fmaf(v.z, w2, fmaf(v.w, w3, acc[r]))));
        }
    }
#pragma unroll
    for (int r = 0; r < 16; ++r) ts[rb + r][j] = silu_f(acc[r]);
    __syncthreads();
    {
        const float b2 = ub2[j];
#pragma unroll
        for (int r = 0; r < 16; ++r) acc[r] = b2;
    }
    for (int kq = 0; kq < H / 4; ++kq) {
        const int k = kq * 4;
        const float w0 = uW2[(k + 0) * H + j];
        const float w1 = uW2[(k + 1) * H + j];
        const float w2 = uW2[(k + 2) * H + j];
        const float w3 = uW2[(k + 3) * H + j];
#pragma unroll
        for (int r = 0; r < 16; ++r) {
            const float4 v = *(const float4*)&ts[rb + r][k];
            acc[r] = fmaf(v.x, w0, fmaf(v.y, w1, fmaf(v.z, w2, fmaf(v.w, w3, acc[r]))));
        }
    }
#pragma unroll
    for (int r = 0; r < 16; ++r) {
        int n = n0 + rb + r;
        if (n < N) out[(size_t)n * H + j] = x[(size_t)n * H + j] + acc[r];
    }
}

extern "C" void kernel_launch(void* const* d_in, const int* in_sizes, int n_in,
                              void* d_out, int out_size, void* d_ws, size_t ws_size,
                              hipStream_t stream) {
    const float* x   = (const float*)d_in[0];
    const int*   ei  = (const int*)  d_in[1];
    const float* ea  = (const float*)d_in[2];
    const float* fW1 = (const float*)d_in[3];
    const float* fb1 = (const float*)d_in[4];
    const float* fW2 = (const float*)d_in[5];
    const float* fb2 = (const float*)d_in[6];
    const float* dW  = (const float*)d_in[7];
    const float* db  = (const float*)d_in[8];
    const float* uW1 = (const float*)d_in[9];
    const float* ub1 = (const float*)d_in[10];
    const float* uW2 = (const float*)d_in[11];
    const float* ub2 = (const float*)d_in[12];

    float* out = (float*)d_out;
    const int N = in_sizes[0] / H;
    const int E = in_sizes[1] / 2;
    const int* src = ei;
    const int* dst = ei + E;

    char* ws = (char*)d_ws;
    size_t off = 0;
    auto alloc = [&](size_t bytes) { void* p = ws + off; off = (off + bytes + 255) & ~(size_t)255; return p; };
    f16* h      = (f16*)alloc((size_t)N * H * sizeof(f16));
    f16* Wt1    = (f16*)alloc((size_t)H * K1 * sizeof(f16));
    f16* Wt2    = (f16*)alloc((size_t)H * H * sizeof(f16));
    int* counts = (int*)alloc((size_t)N * sizeof(int));
    int* ofs    = (int*)alloc((size_t)N * sizeof(int));     // becomes cursor in scatter
    int* rk     = (int*)alloc((size_t)E * sizeof(int));     // rank (full) or perm (fallback)
    int* nstart = (int*)alloc((size_t)(NBLK + 1) * sizeof(int));
    int* estart = (int*)alloc((size_t)(NBLK + 1) * sizeof(int));
    size_t base = off;
    f16* ea16   = (f16*)(ws + base);
    const size_t need_full = base + (size_t)E * ROWF * sizeof(f16);
    const bool full = (ws_size >= need_full);

    const int nscan = (N + 255) / 256;       // 196 <= 256
    const int ntiles = (E + EB - 1) / EB;

    hipMemsetAsync(counts, 0, (size_t)N * sizeof(int), stream);
    convert_weights_kernel<<<(H * K1 + H * H + 255) / 256, 256, 0, stream>>>(fW1, fW2, Wt1, Wt2);
    compute_h_kernel<<<(N + NB - 1) / NB, 256, 0, stream>>>(x, dW, db, h, N);

    hist_kernel<<<1024, 256, 0, stream>>>(dst, counts, E);
    scan1_kernel<<<nscan, 256, 0, stream>>>(counts, ofs, counts /*reuse as bsum*/, N);
    // careful: bsum must not alias scanned region; reuse counts (done with it)
    scan2_kernel<<<1, 256, 0, stream>>>(counts, nscan);
    scan3_kernel<<<nscan, 256, 0, stream>>>(ofs, counts, N);

    if (full) {
        ranges_kernel<<<(NBLK + 256) / 256, 256, 0, stream>>>(ofs, nstart, estart, N, E, NBLK);
        scatter_rank_kernel<<<1024, 256, 0, stream>>>(dst, ofs, rk, E);
        permute_ea_kernel<<<2048, 256, 0, stream>>>(ea, src, dst, rk, ea16, E, ntiles);
        edge_grouped_kernel<<<NBLK, 256, 0, stream>>>(
            ea16, Wt1, Wt2, fb1, fb2, h, out, nstart, estart);
    } else {
        hipMemsetAsync(out, 0, (size_t)N * H * sizeof(float), stream);
        scatter_perm_kernel<<<1024, 256, 0, stream>>>(dst, ofs, rk, E);
        const int nblk = (ntiles < 4096) ? ntiles : 4096;
        edge_perm_kernel<<<nblk, 256, 0, stream>>>(
            ea, src, dst, rk, Wt1, Wt2, fb1, fb2, h, out, E, ntiles);
    }

    update_kernel<<<(N + NB - 1) / NB, 256, 0, stream>>>(
        x, uW1, ub1, uW2, ub2, out, N);
}